// Round 1
// baseline (2033.621 us; speedup 1.0000x reference)
//
#include <hip/hip_runtime.h>
#include <hip/hip_bf16.h>
#include <hip/hip_cooperative_groups.h>
#include <math.h>

namespace cg = cooperative_groups;

#define NNODES 50000
#define NEDGES 500000
#define NLAYERS 8
#define NSCANB 196  // ceil(NNODES/256)
#define CSRMAX (NEDGES + 3 * NNODES)  // padded-to-4 worst case
#define NTILES 391  // ceil(NNODES/128)

typedef __attribute__((ext_vector_type(8))) short bhalf8;
typedef __attribute__((ext_vector_type(4))) float f32x4;

// K-dim permutation: packed pos p <-> natural dim d = 16*(p&7) + (p>>3).
static __device__ __forceinline__ int invp(int p) { return 16 * (p & 7) + (p >> 3); }

static __device__ __forceinline__ unsigned short f2b(float v) {
    unsigned u = __builtin_bit_cast(unsigned, v);
    u += 0x7fffu + ((u >> 16) & 1u);
    return (unsigned short)(u >> 16);
}
static __device__ __forceinline__ float b2f(unsigned short w) {
    return __builtin_bit_cast(float, (unsigned)w << 16);
}
static __device__ __forceinline__ float b2f_lo(unsigned w) {
    return __builtin_bit_cast(float, w << 16);
}
static __device__ __forceinline__ float b2f_hi(unsigned w) {
    return __builtin_bit_cast(float, w & 0xffff0000u);
}
static __device__ __forceinline__ float ub(unsigned a, int k) {
    return (float)((a >> (8 * k)) & 0xffu);  // folds to v_cvt_f32_ubyteN
}

// ---------------- graph preprocessing ----------------

__global__ void k_count(const int* __restrict__ col, int* __restrict__ counts) {
    int e = blockIdx.x * 256 + threadIdx.x;
    if (e < NEDGES) atomicAdd(&counts[col[e]], 1);
}

__global__ __launch_bounds__(256) void k_dinv_bsum(const int* __restrict__ counts,
                                                   float* __restrict__ dinv,
                                                   int* __restrict__ part) {
    __shared__ int ls[256];
    int t = threadIdx.x, i = blockIdx.x * 256 + t;
    int cnt = (i < NNODES) ? counts[i] : 0;
    if (i < NNODES) dinv[i] = rsqrtf((float)(cnt + 1));
    ls[t] = (i < NNODES) ? ((cnt + 3) & ~3) : 0;
    __syncthreads();
    for (int o = 128; o > 0; o >>= 1) {
        if (t < o) ls[t] += ls[t + o];
        __syncthreads();
    }
    if (t == 0) part[blockIdx.x] = ls[0];
}

__global__ __launch_bounds__(256) void k_pscan(int* __restrict__ part) {
    __shared__ int ls[256];
    int t = threadIdx.x;
    int v = (t < NSCANB) ? part[t] : 0;
    ls[t] = v;
    __syncthreads();
    for (int o = 1; o < 256; o <<= 1) {
        int x = (t >= o) ? ls[t - o] : 0;
        __syncthreads();
        ls[t] += x;
        __syncthreads();
    }
    if (t < NSCANB) part[t] = ls[t] - v;
}

__global__ __launch_bounds__(256) void k_offs(const int* __restrict__ counts,
                                              const int* __restrict__ part,
                                              int* __restrict__ offs) {
    __shared__ int ls[256];
    int t = threadIdx.x, i = blockIdx.x * 256 + t;
    int v = (i < NNODES) ? ((counts[i] + 3) & ~3) : 0;
    ls[t] = v;
    __syncthreads();
    for (int o = 1; o < 256; o <<= 1) {
        int x = (t >= o) ? ls[t - o] : 0;
        __syncthreads();
        ls[t] += x;
        __syncthreads();
    }
    int excl = part[blockIdx.x] + ls[t] - v;
    if (i < NNODES) offs[i] = excl;
    if (i == NNODES - 1) offs[NNODES] = excl + v;
}

// csr pre-memset to 0 -> pad entries are {row 0, w 0.0f}
__global__ void k_scatter(const int* __restrict__ row, const int* __restrict__ col,
                          const int* __restrict__ offs, int* __restrict__ cursor,
                          const float* __restrict__ dinv, int2* __restrict__ csr) {
    int e = blockIdx.x * 256 + threadIdx.x;
    if (e < NEDGES) {
        int c = col[e], r = row[e];
        int pos = offs[c] + atomicAdd(&cursor[c], 1);
        float w = dinv[r] * dinv[c];
        csr[pos] = make_int2(r, __builtin_bit_cast(int, w));
    }
}

// ---------------- folded + packed layer weights (K-permuted) ----------------
__global__ void k_wcp2(const float* __restrict__ w1, const float* __restrict__ w2,
                       unsigned short* __restrict__ Wp) {
    int idx = blockIdx.x * 256 + threadIdx.x;
    if (idx >= NLAYERS * 32768) return;
    int i = idx >> 15;
    int rem = idx & 32767;
    int s = rem >> 12;
    int t = (rem >> 9) & 7;
    int lane = (rem >> 3) & 63;
    int j = rem & 7;
    int kf = s * 32 + (lane >> 4) * 8 + j;
    int n = t * 16 + (lane & 15);
    float beta = logf(1.0f / (float)(i + 1) + 1.0f);
    float v;
    if (kf < 128) {
        int k = invp(kf);
        v = beta * w1[(i * 128 + k) * 128 + n] + ((k == n) ? (1.0f - beta) : 0.0f);
    } else {
        int k2 = invp(kf - 128);
        v = 0.5f * (beta * w2[(i * 128 + k2) * 128 + n] + ((k2 == n) ? (1.0f - beta) : 0.0f));
    }
    Wp[idx] = f2b(v);
}

// ---------------- lin1 (MFMA): h0 -> h0s (128 shorts/row, packed) ----------------
__global__ __launch_bounds__(256) void k_lin1m(const float* __restrict__ x,
                                               const float* __restrict__ W,
                                               const float* __restrict__ b,
                                               unsigned short* __restrict__ h0s) {
    __shared__ __attribute__((aligned(16))) unsigned short Bs[8192];
    int t = threadIdx.x;
    for (int idx = t; idx < 8192; idx += 256) {
        int s = idx >> 12;
        int tt = (idx >> 9) & 7;
        int lane = (idx >> 3) & 63;
        int j = idx & 7;
        int k = s * 32 + (lane >> 4) * 8 + j;
        int n = tt * 16 + (lane & 15);
        Bs[idx] = f2b(W[k * 128 + n]);
    }
    __syncthreads();

    int w = t >> 6, lane = t & 63;
    int q = lane >> 4, r = lane & 15;
    int m0 = blockIdx.x * 64 + w * 16;
    int mA = m0 + r; if (mA > NNODES - 1) mA = NNODES - 1;
    const float* xrow = x + (size_t)mA * 64;

    f32x4 acc[8];
#pragma unroll
    for (int tt = 0; tt < 8; ++tt) {
        float bv = b[tt * 16 + r];
        acc[tt] = (f32x4){bv, bv, bv, bv};
    }
#pragma unroll
    for (int s = 0; s < 2; ++s) {
        float xv[8];
        *(float4*)&xv[0] = *(const float4*)(xrow + s * 32 + q * 8);
        *(float4*)&xv[4] = *(const float4*)(xrow + s * 32 + q * 8 + 4);
        bhalf8 ah, al;
#pragma unroll
        for (int j = 0; j < 8; ++j) {
            unsigned short hb = f2b(xv[j]);
            ah[j] = (short)hb;
            al[j] = (short)f2b(xv[j] - b2f(hb));
        }
#pragma unroll
        for (int tt = 0; tt < 8; ++tt) {
            bhalf8 bf = *(const bhalf8*)&Bs[((s * 8 + tt) << 9) + lane * 8];
            acc[tt] = __builtin_amdgcn_mfma_f32_16x16x32_bf16(ah, bf, acc[tt], 0, 0, 0);
            acc[tt] = __builtin_amdgcn_mfma_f32_16x16x32_bf16(al, bf, acc[tt], 0, 0, 0);
        }
    }
#pragma unroll
    for (int i = 0; i < 4; ++i) {
        int mm = m0 + q * 4 + i;
        if (mm < NNODES) {
            bhalf8 hv;
#pragma unroll
            for (int tt = 0; tt < 8; ++tt) hv[tt] = (short)f2b(acc[tt][i]);
            *(bhalf8*)&h0s[(size_t)mm * 128 + 8 * r] = hv;
        }
    }
}

// ---------------- persistent cooperative mega-kernel: 8x(spmm+gemm -> actq) + lin2 ----
// Per block, per tile (128 rows): spmm aggregates into XOR-swizzled LDS (no global
// agg round-trip), then MFMA GEMM M=128 N=128 K=256 with B-frags straight from L2.
// grid.sync separates {outb+stats done} -> actq -> {hact/qs done} -> next layer.
__global__ __launch_bounds__(256, 2) void k_mega(
    const unsigned short* __restrict__ h0s,
    const int* __restrict__ offs,
    const int2* __restrict__ csr,
    const float* __restrict__ dinv,
    const unsigned short* __restrict__ Wp,
    const float* __restrict__ norm_w,
    const float* __restrict__ norm_b,
    const float* __restrict__ lin2_w,
    const float* __restrict__ lin2_b,
    unsigned char* __restrict__ hact,
    float* __restrict__ qs,
    unsigned short* __restrict__ outb,
    float* __restrict__ stats,
    float* __restrict__ out) {
    __shared__ __attribute__((aligned(16))) unsigned char As[32768];  // 128x128 bf16, swizzled
    __shared__ float red[512];
    __shared__ float skp[128], ckp[128];
    cg::grid_group gg = cg::this_grid();

    const unsigned char* h0b = (const unsigned char*)h0s;
    int t = threadIdx.x;
    int G = gridDim.x;
    const float Mf = (float)NNODES * 128.0f;

    int w = t >> 6, lane = t & 63;
    int q = lane >> 4, r = lane & 15;

    for (int layer = 0; layer < NLAYERS; ++layer) {
        const unsigned short* Bp = Wp + (size_t)layer * 32768;
        float ps1 = 0.f, ps2 = 0.f;
#pragma unroll 1
        for (int tile = blockIdx.x; tile < NTILES; tile += G) {
            int m0 = tile * 128;
            // ---- phase S: spmm for this block's 128 rows -> LDS (swizzled) ----
            {
                int g = t >> 5;
                unsigned sl = t & 31;
                unsigned s4 = sl * 4, s8 = sl * 8;
#pragma unroll 1
                for (int rr = 0; rr < 16; ++rr) {
                    int rl = g * 16 + rr;
                    int c = m0 + rl;
                    uint2 outv = make_uint2(0u, 0u);
                    if (c < NNODES) {
                        float di = dinv[c];
                        float dw = di * di;
                        float a0, a1, a2, a3;
                        int e = offs[c], e1 = offs[c + 1];
                        if (layer == 0) {
                            uint2 gv = *(const uint2*)(h0b + (((unsigned)c << 8) + s8));
                            a0 = dw * b2f_lo(gv.x); a1 = dw * b2f_hi(gv.x);
                            a2 = dw * b2f_lo(gv.y); a3 = dw * b2f_hi(gv.y);
                            for (; e < e1; e += 4) {
                                int2 E[4];
#pragma unroll
                                for (int u = 0; u < 4; ++u) E[u] = csr[e + u];
                                uint2 gvu[4];
#pragma unroll
                                for (int u = 0; u < 4; ++u)
                                    gvu[u] = *(const uint2*)(h0b + (((unsigned)E[u].x << 8) + s8));
#pragma unroll
                                for (int u = 0; u < 4; ++u) {
                                    float wv = __builtin_bit_cast(float, E[u].y);
                                    a0 = fmaf(wv, b2f_lo(gvu[u].x), a0);
                                    a1 = fmaf(wv, b2f_hi(gvu[u].x), a1);
                                    a2 = fmaf(wv, b2f_lo(gvu[u].y), a2);
                                    a3 = fmaf(wv, b2f_hi(gvu[u].y), a3);
                                }
                            }
                        } else {
                            unsigned av = *(const unsigned*)(hact + (((unsigned)c << 7) + s4));
                            float dws = dw * qs[c];
                            a0 = dws * ub(av, 0); a1 = dws * ub(av, 1);
                            a2 = dws * ub(av, 2); a3 = dws * ub(av, 3);
                            for (; e < e1; e += 4) {
                                int2 E[4];
#pragma unroll
                                for (int u = 0; u < 4; ++u) E[u] = csr[e + u];
                                unsigned au[4];
                                float wv[4];
#pragma unroll
                                for (int u = 0; u < 4; ++u) {
                                    wv[u] = __builtin_bit_cast(float, E[u].y) * qs[E[u].x];
                                    au[u] = *(const unsigned*)(hact + (((unsigned)E[u].x << 7) + s4));
                                }
#pragma unroll
                                for (int u = 0; u < 4; ++u) {
                                    a0 = fmaf(wv[u], ub(au[u], 0), a0);
                                    a1 = fmaf(wv[u], ub(au[u], 1), a1);
                                    a2 = fmaf(wv[u], ub(au[u], 2), a2);
                                    a3 = fmaf(wv[u], ub(au[u], 3), a3);
                                }
                            }
                        }
                        outv.x = (unsigned)f2b(0.5f * a0) | ((unsigned)f2b(0.5f * a1) << 16);
                        outv.y = (unsigned)f2b(0.5f * a2) | ((unsigned)f2b(0.5f * a3) << 16);
                    }
                    unsigned ob = ((unsigned)(rl * 256) + s8) ^ (((unsigned)rl & 7u) << 4);
                    *(uint2*)(As + ob) = outv;
                }
            }
            __syncthreads();
            // ---- phase G: GEMM M=128 N=128 K=256 (agg from LDS, h0 + B from L2) ----
            int rl0 = w * 32 + r, rl1 = rl0 + 16;
            int mA0 = m0 + rl0; if (mA0 > NNODES - 1) mA0 = NNODES - 1;
            int mA1 = m0 + rl1; if (mA1 > NNODES - 1) mA1 = NNODES - 1;
            const unsigned short* h0r0 = h0s + (size_t)mA0 * 128 + q * 8;
            const unsigned short* h0r1 = h0s + (size_t)mA1 * 128 + q * 8;
            f32x4 acc[2][8];
#pragma unroll
            for (int ms = 0; ms < 2; ++ms)
#pragma unroll
                for (int nt = 0; nt < 8; ++nt) acc[ms][nt] = (f32x4){0.f, 0.f, 0.f, 0.f};
#pragma unroll
            for (int sk = 0; sk < 8; ++sk) {
                bhalf8 a0, a1;
                if (sk < 4) {
                    a0 = *(const bhalf8*)(As + (((unsigned)(rl0 * 256 + sk * 64 + q * 16)) ^ (((unsigned)rl0 & 7u) << 4)));
                    a1 = *(const bhalf8*)(As + (((unsigned)(rl1 * 256 + sk * 64 + q * 16)) ^ (((unsigned)rl1 & 7u) << 4)));
                } else {
                    a0 = *(const bhalf8*)(h0r0 + (sk - 4) * 32);
                    a1 = *(const bhalf8*)(h0r1 + (sk - 4) * 32);
                }
#pragma unroll
                for (int nt = 0; nt < 8; ++nt) {
                    bhalf8 bfr = *(const bhalf8*)&Bp[((sk * 8 + nt) << 9) + lane * 8];
                    acc[0][nt] = __builtin_amdgcn_mfma_f32_16x16x32_bf16(a0, bfr, acc[0][nt], 0, 0, 0);
                    acc[1][nt] = __builtin_amdgcn_mfma_f32_16x16x32_bf16(a1, bfr, acc[1][nt], 0, 0, 0);
                }
            }
#pragma unroll
            for (int ms = 0; ms < 2; ++ms) {
#pragma unroll
                for (int i = 0; i < 4; ++i) {
                    int mm = m0 + w * 32 + ms * 16 + q * 4 + i;
                    if (mm < NNODES) {
                        bhalf8 hv;
#pragma unroll
                        for (int nt = 0; nt < 8; ++nt) {
                            float v = acc[ms][nt][i];
                            ps1 += v; ps2 += v * v;
                            hv[nt] = (short)f2b(v);
                        }
                        *(bhalf8*)&outb[(size_t)mm * 128 + 8 * r] = hv;
                    }
                }
            }
            __syncthreads();  // As reused by next tile
        }
        // ---- block stats reduction + global accumulate ----
        red[t] = ps1; red[256 + t] = ps2;
        __syncthreads();
        for (int o = 128; o > 0; o >>= 1) {
            if (t < o) { red[t] += red[t + o]; red[256 + t] += red[256 + t + o]; }
            __syncthreads();
        }
        if (t == 0) {
            atomicAdd(&stats[2 * layer], red[0]);
            atomicAdd(&stats[2 * layer + 1], red[256]);
        }
        gg.sync();

        if (layer < NLAYERS - 1) {
            // ---- phase A: actq on this block's rows (outb is L2-hot) ----
            float mean = stats[2 * layer] / Mf;
            float var = stats[2 * layer + 1] / Mf - mean * mean;
            float inv = 1.0f / (sqrtf(fmaxf(var, 0.0f)) + 1e-5f);
            if (t < 128) {
                int d = invp(t);
                float sks = inv * norm_w[layer * 128 + d];
                skp[t] = sks;
                ckp[t] = norm_b[layer * 128 + d] - mean * sks;
            }
            __syncthreads();
            int sl = t & 31;
#pragma unroll 1
            for (int tile = blockIdx.x; tile < NTILES; tile += G) {
#pragma unroll 1
                for (int pass = 0; pass < 16; ++pass) {
                    int row = tile * 128 + pass * 8 + (t >> 5);
                    if (row < NNODES) {
                        uint2 gv = *(const uint2*)(outb + (size_t)row * 128 + sl * 4);
                        float h[4];
                        h[0] = fmaxf(fmaf(b2f_lo(gv.x), skp[4 * sl + 0], ckp[4 * sl + 0]), 0.0f);
                        h[1] = fmaxf(fmaf(b2f_hi(gv.x), skp[4 * sl + 1], ckp[4 * sl + 1]), 0.0f);
                        h[2] = fmaxf(fmaf(b2f_lo(gv.y), skp[4 * sl + 2], ckp[4 * sl + 2]), 0.0f);
                        h[3] = fmaxf(fmaf(b2f_hi(gv.y), skp[4 * sl + 3], ckp[4 * sl + 3]), 0.0f);
                        float rmax = fmaxf(fmaxf(h[0], h[1]), fmaxf(h[2], h[3]));
#pragma unroll
                        for (int o = 1; o < 32; o <<= 1) rmax = fmaxf(rmax, __shfl_xor(rmax, o));
                        float rs = (rmax > 0.f) ? 255.0f / rmax : 0.0f;
                        unsigned pk = 0;
#pragma unroll
                        for (int k = 0; k < 4; ++k) {
                            float a = fminf(h[k] * rs, 255.0f);
                            pk |= __float2uint_rn(a) << (8 * k);
                        }
                        *(unsigned*)(hact + (size_t)row * 128 + sl * 4) = pk;
                        if (sl == 0) qs[row] = (rmax > 0.f) ? rmax * (1.0f / 255.0f) : 0.0f;
                    }
                }
            }
            gg.sync();
        }
    }
    // ---- phase L: lin2 with fused final LayerNorm+ReLU ----
    {
        float mean = stats[14] / Mf;
        float var = stats[15] / Mf - mean * mean;
        float inv = 1.0f / (sqrtf(fmaxf(var, 0.0f)) + 1e-5f);
        unsigned short* Bs2 = (unsigned short*)As;
        for (int idx = t; idx < 8192; idx += 256) {
            int s = idx >> 11;
            int tt = (idx >> 9) & 3;
            int ln = (idx >> 3) & 63;
            int j = idx & 7;
            int kf = s * 32 + (ln >> 4) * 8 + j;
            int k = invp(kf);
            int n = tt * 16 + (ln & 15);
            Bs2[idx] = f2b(lin2_w[k * 64 + n]);
        }
        if (t < 128) {
            int d = invp(t);
            float sks = inv * norm_w[7 * 128 + d];
            skp[t] = sks;
            ckp[t] = norm_b[7 * 128 + d] - mean * sks;
        }
        __syncthreads();
#pragma unroll 1
        for (int chunk = blockIdx.x; chunk < 782; chunk += G) {
            int m0 = chunk * 64 + w * 16;
            int mA = m0 + r; if (mA > NNODES - 1) mA = NNODES - 1;
            const unsigned short* arow = outb + (size_t)mA * 128;
            f32x4 acc2[4];
#pragma unroll
            for (int tt = 0; tt < 4; ++tt) {
                float bv = lin2_b[tt * 16 + r];
                acc2[tt] = (f32x4){bv, bv, bv, bv};
            }
#pragma unroll
            for (int s = 0; s < 4; ++s) {
                bhalf8 raw = *(const bhalf8*)(arow + s * 32 + q * 8);
                bhalf8 af;
#pragma unroll
                for (int j = 0; j < 8; ++j) {
                    int ppos = s * 32 + q * 8 + j;
                    float v = b2f((unsigned short)raw[j]);
                    v = fmaxf(fmaf(v, skp[ppos], ckp[ppos]), 0.0f);
                    af[j] = (short)f2b(v);
                }
#pragma unroll
                for (int tt = 0; tt < 4; ++tt) {
                    bhalf8 bf = *(const bhalf8*)&Bs2[((s * 4 + tt) << 9) + lane * 8];
                    acc2[tt] = __builtin_amdgcn_mfma_f32_16x16x32_bf16(af, bf, acc2[tt], 0, 0, 0);
                }
            }
#pragma unroll
            for (int i = 0; i < 4; ++i) {
                int mm = m0 + q * 4 + i;
                if (mm < NNODES) {
#pragma unroll
                    for (int tt = 0; tt < 4; ++tt)
                        out[(size_t)mm * 64 + tt * 16 + r] = acc2[tt][i];
                }
            }
        }
    }
}

// ---------------- launch ----------------

extern "C" void kernel_launch(void* const* d_in, const int* in_sizes, int n_in,
                              void* d_out, int out_size, void* d_ws, size_t ws_size,
                              hipStream_t stream) {
    const float* x      = (const float*)d_in[0];
    const int*   ei     = (const int*)d_in[1];
    const float* lin1_w = (const float*)d_in[2];
    const float* lin1_b = (const float*)d_in[3];
    const float* w1     = (const float*)d_in[4];
    const float* w2     = (const float*)d_in[5];
    const float* norm_w = (const float*)d_in[6];
    const float* norm_b = (const float*)d_in[7];
    const float* lin2_w = (const float*)d_in[8];
    const float* lin2_b = (const float*)d_in[9];
    float* out = (float*)d_out;

    const int* row = ei;
    const int* col = ei + NEDGES;

    char* p = (char*)d_ws;
    auto take = [&](size_t bytes) -> char* {
        char* r = p;
        p += (bytes + 255) & ~(size_t)255;
        return r;
    };
    unsigned short* h0s  = (unsigned short*)take((size_t)NNODES * 128 * 2);  // h0 bf16 packed
    unsigned short* outb = (unsigned short*)take((size_t)NNODES * 128 * 2);  // layer out bf16 packed
    unsigned char*  hact = (unsigned char*)take((size_t)NNODES * 128);       // activated u8
    float*          qs   = (float*)take((size_t)NNODES * 4);                 // per-row dequant scale
    unsigned short* Wp   = (unsigned short*)take((size_t)NLAYERS * 32768 * 2);
    float* dinv    = (float*)take((size_t)NNODES * 4);
    // contiguous zero-init zone: counts | cursor | stats
    char* zzone    = take((size_t)NNODES * 4 * 2 + 256);
    int*   counts  = (int*)zzone;
    int*   cursor  = (int*)(zzone + (size_t)NNODES * 4);
    float* stats   = (float*)(zzone + (size_t)NNODES * 4 * 2);
    int*   offs    = (int*)take((size_t)(NNODES + 1) * 4);
    int*   part    = (int*)take((size_t)NSCANB * 4);
    int2*  csr     = (int2*)take((size_t)CSRMAX * 8);

    hipMemsetAsync(zzone, 0, (size_t)NNODES * 4 * 2 + 256, stream);
    hipMemsetAsync(csr, 0, (size_t)CSRMAX * 8, stream);  // pads = {row 0, w 0}

    k_count<<<(NEDGES + 255) / 256, 256, 0, stream>>>(col, counts);
    k_dinv_bsum<<<NSCANB, 256, 0, stream>>>(counts, dinv, part);
    k_pscan<<<1, 256, 0, stream>>>(part);
    k_offs<<<NSCANB, 256, 0, stream>>>(counts, part, offs);
    k_scatter<<<(NEDGES + 255) / 256, 256, 0, stream>>>(row, col, offs, cursor, dinv, csr);
    k_wcp2<<<(NLAYERS * 32768 + 255) / 256, 256, 0, stream>>>(w1, w2, Wp);
    k_lin1m<<<(NNODES + 63) / 64, 256, 0, stream>>>(x, lin1_w, lin1_b, h0s);

    // cooperative grid: one tile per block when capacity allows, strided otherwise
    int nb = 0;
    hipOccupancyMaxActiveBlocksPerMultiprocessor(&nb, k_mega, 256, 0);
    if (nb < 1) nb = 1;
    int G = nb * 256;
    if (G > NTILES) G = NTILES;

    const unsigned short* a_h0s = h0s;
    const int* a_offs = offs;
    const int2* a_csr = csr;
    const float* a_dinv = dinv;
    const unsigned short* a_Wp = Wp;
    const float* a_nw = norm_w;
    const float* a_nb = norm_b;
    const float* a_l2w = lin2_w;
    const float* a_l2b = lin2_b;
    unsigned char* a_hact = hact;
    float* a_qs = qs;
    unsigned short* a_outb = outb;
    float* a_stats = stats;
    float* a_out = out;
    void* margs[] = {&a_h0s, &a_offs, &a_csr, &a_dinv, &a_Wp, &a_nw, &a_nb,
                     &a_l2w, &a_l2b, &a_hact, &a_qs, &a_outb, &a_stats, &a_out};
    hipLaunchCooperativeKernel(k_mega, dim3(G), dim3(256), margs, 0, stream);
}